// Round 8
// baseline (367.133 us; speedup 1.0000x reference)
//
#include <hip/hip_runtime.h>
#include <stdint.h>

#define NNODES 50000
#define NEDGES 800000
#define DIM 128
#define IN1 512
#define IN2 384
#define NSB 196   // ceil(NNODES/256)
#define PT 5      // tiles per edge2 block (800000 = 2500*5*64)

typedef __attribute__((ext_vector_type(8))) short bf16x8;
typedef __attribute__((ext_vector_type(8))) unsigned short u16x8;
typedef __attribute__((ext_vector_type(4))) float f32x4;
typedef __attribute__((ext_vector_type(4))) uint32_t u32x4;

__device__ __forceinline__ unsigned short f2bf(float f) {
  union { float f; uint32_t u; } v; v.f = f;
  return (unsigned short)((v.u + 0x7FFFu + ((v.u >> 16) & 1u)) >> 16);
}
__device__ __forceinline__ float bf2f(unsigned short u) {
  union { uint32_t u; float f; } v; v.u = ((uint32_t)u) << 16;
  return v.f;
}
__device__ __forceinline__ uint32_t cvtpk(float lo, float hi) {
  uint32_t r;
  asm volatile("v_cvt_pk_bf16_f32 %0, %1, %2" : "=v"(r) : "v"(lo), "v"(hi));
  return r;
}

__device__ __forceinline__ void cvt8(const float* __restrict__ p, unsigned short* dst, int sidx) {
  float4 f0 = *(const float4*)(p);
  float4 f1 = *(const float4*)(p + 4);
  u16x8 o;
  o[0] = f2bf(f0.x); o[1] = f2bf(f0.y); o[2] = f2bf(f0.z); o[3] = f2bf(f0.w);
  o[4] = f2bf(f1.x); o[5] = f2bf(f1.y); o[6] = f2bf(f1.z); o[7] = f2bf(f1.w);
  *(u16x8*)(dst + sidx) = o;
}

// 128x128x128 macro-tile, 4 waves as 2x2 of 64x64 (p1/node/fallback)
__device__ __forceinline__ void mfma128(const unsigned short* As, const unsigned short* Bs,
                                        f32x4 acc[4][4], int wm, int wn, int l) {
#pragma unroll
  for (int kk = 0; kk < 4; ++kk) {
    bf16x8 a[4], b[4];
#pragma unroll
    for (int mi = 0; mi < 4; ++mi) {
      int row = wm * 64 + mi * 16 + (l & 15);
      int idx = (row * 128 + kk * 32 + (l >> 4) * 8) ^ ((row & 7) << 3);
      a[mi] = *(const bf16x8*)(As + idx);
    }
#pragma unroll
    for (int ni = 0; ni < 4; ++ni) {
      int nrow = wn * 64 + ni * 16 + (l & 15);
      int idx = (nrow * 128 + kk * 32 + (l >> 4) * 8) ^ ((nrow & 7) << 3);
      b[ni] = *(const bf16x8*)(Bs + idx);
    }
#pragma unroll
    for (int mi = 0; mi < 4; ++mi)
#pragma unroll
      for (int ni = 0; ni < 4; ++ni)
        acc[mi][ni] = __builtin_amdgcn_mfma_f32_16x16x32_bf16(a[mi], b[ni], acc[mi][ni], 0, 0, 0);
  }
}

// ---------------- zero: agg (float4) + count ----------------
__global__ void zero_kernel(float4* __restrict__ a, int n4, int* __restrict__ c, int nc) {
  int i = blockIdx.x * 256 + threadIdx.x;
  int stride = gridDim.x * 256;
  for (int k = i; k < n4; k += stride) a[k] = float4{0.f, 0.f, 0.f, 0.f};
  for (int k = i; k < nc; k += stride) c[k] = 0;
}

// ---------------- wconv+p0: 5 pre-swizzled bf16 weight tiles, plus Ud/Uc ----------------
__global__ void wconv_p0_kernel(const float* __restrict__ W1, const float* __restrict__ W2,
                                const float* __restrict__ u, const float* __restrict__ b1,
                                const float* __restrict__ b2,
                                unsigned short* __restrict__ Wt,
                                float* __restrict__ Ud, float* __restrict__ Uc) {
  int b = blockIdx.x;
  if (b < 320) {
    int t = b * 256 + threadIdx.x;
    int tile = t >> 14, rem = t & 16383, n = rem >> 7, k = rem & 127;
    float v = (tile < 3) ? W1[(size_t)n * IN1 + tile * 128 + k]
                         : W2[(size_t)n * IN2 + (tile - 3) * 128 + k];
    int lin = ((n * 128 + (k & ~7)) ^ ((n & 7) << 3)) | (k & 7);
    Wt[tile * 16384 + lin] = f2bf(v);
  } else {
    int g = (b - 320) * 2 + (threadIdx.x >> 7);
    int c = threadIdx.x & 127;
    const float* ur = u + (size_t)g * DIM;
    const float* w1 = W1 + (size_t)c * IN1 + 384;
    const float* w2 = W2 + (size_t)c * IN2 + 256;
    float s1 = b1[c], s2 = b2[c];
    for (int k = 0; k < DIM; ++k) { float uv = ur[k]; s1 += uv * w1[k]; s2 += uv * w2[k]; }
    Ud[g * DIM + c] = s1;
    Uc[g * DIM + c] = s2;
  }
}

// ---------------- P1: Xad/Xb/Yx per-node precompute ----------------
__global__ __launch_bounds__(256, 2) void p1_kernel(
    const float* __restrict__ x, const int* __restrict__ batch,
    const unsigned short* __restrict__ Wt,
    const float* __restrict__ Ud, const float* __restrict__ Uc,
    unsigned short* __restrict__ Xad, unsigned short* __restrict__ Xb,
    unsigned short* __restrict__ Yx) {
  __shared__ __align__(16) unsigned short As[128 * 128];
  __shared__ __align__(16) unsigned short Bs[128 * 128];
  const int t = threadIdx.x, l = t & 63, w = t >> 6, wm = w >> 1, wn = w & 1;
  const int n0 = blockIdx.x * 128, r = t >> 1, h = t & 1;
  const int swz = (r & 7) << 3;
  {
    int n = n0 + r; if (n >= NNODES) n = NNODES - 1;
    const float* rowp = x + (size_t)n * DIM + h * 64;
#pragma unroll
    for (int i = 0; i < 8; ++i) cvt8(rowp + i * 8, As, (r * 128 + h * 64 + i * 8) ^ swz);
  }
#pragma unroll
  for (int p = 0; p < 3; ++p) {
    __syncthreads();
    {
      const u16x8* wsrc = (const u16x8*)(Wt + (size_t)((p == 2) ? 3 : p) * 16384);
      u16x8* bdst = (u16x8*)Bs;
#pragma unroll
      for (int i = 0; i < 8; ++i) bdst[t + i * 256] = wsrc[t + i * 256];
    }
    __syncthreads();
    f32x4 acc[4][4] = {};
    mfma128(As, Bs, acc, wm, wn, l);
#pragma unroll
    for (int mi = 0; mi < 4; ++mi)
#pragma unroll
      for (int rr = 0; rr < 4; ++rr) {
        int m = wm * 64 + mi * 16 + (l >> 4) * 4 + rr;
        int n = n0 + m;
        if (n < NNODES) {
          int g = batch[n];
#pragma unroll
          for (int ni = 0; ni < 4; ++ni) {
            int col = wn * 64 + ni * 16 + (l & 15);
            float v = acc[mi][ni][rr];
            if (p == 0)      Xad[(size_t)n * DIM + col] = f2bf(v + Ud[g * DIM + col]);
            else if (p == 1) Xb [(size_t)n * DIM + col] = f2bf(v);
            else             Yx [(size_t)n * DIM + col] = f2bf(v + Uc[g * DIM + col]);
          }
        }
      }
  }
}

// ---------------- counting sort by dst ----------------
__global__ void hist_kernel(const int* __restrict__ dstI, int* __restrict__ count) {
  int e = blockIdx.x * 256 + threadIdx.x;
  if (e < NEDGES) atomicAdd(&count[dstI[e]], 1);
}

__global__ void scan1_kernel(const int* __restrict__ count, int* __restrict__ bsum) {
  __shared__ int ws[4];
  int i = blockIdx.x * 256 + threadIdx.x;
  int v = (i < NNODES) ? count[i] : 0;
  int l = threadIdx.x & 63;
#pragma unroll
  for (int off = 32; off > 0; off >>= 1) v += __shfl_down(v, off);
  if (l == 0) ws[threadIdx.x >> 6] = v;
  __syncthreads();
  if (threadIdx.x == 0) bsum[blockIdx.x] = ws[0] + ws[1] + ws[2] + ws[3];
}

__global__ void scan2_kernel(const int* __restrict__ bsum, int* __restrict__ bpre) {
  __shared__ int s[256];
  int i = threadIdx.x;
  int v = (i < NSB) ? bsum[i] : 0;
  s[i] = v; __syncthreads();
  for (int off = 1; off < 256; off <<= 1) {
    int u = (i >= off) ? s[i - off] : 0;
    __syncthreads();
    s[i] += u;
    __syncthreads();
  }
  if (i < NSB) bpre[i] = s[i] - v;   // exclusive
}

__global__ void scan3_kernel(const int* __restrict__ count, const int* __restrict__ bpre,
                             int* __restrict__ rowptr) {
  __shared__ int s[256];
  int b = blockIdx.x, i = threadIdx.x, g = b * 256 + i;
  int v = (g < NNODES) ? count[g] : 0;
  s[i] = v; __syncthreads();
  for (int off = 1; off < 256; off <<= 1) {
    int u = (i >= off) ? s[i - off] : 0;
    __syncthreads();
    s[i] += u;
    __syncthreads();
  }
  if (g < NNODES) rowptr[g] = bpre[b] + s[i] - v;  // exclusive global prefix
}

// destructive on rowptr; one packed 8B write per edge: (e<<32)|(s<<16)|d
__global__ void scatter_kernel(const int* __restrict__ srcI, const int* __restrict__ dstI,
                               int* __restrict__ rowptr, uint64_t* __restrict__ esd) {
  int e = blockIdx.x * 256 + threadIdx.x;
  if (e < NEDGES) {
    int d = dstI[e], s = srcI[e];
    int pos = atomicAdd(&rowptr[d], 1);
    esd[pos] = ((uint64_t)(uint32_t)e << 32) | ((uint32_t)s << 16) | (uint32_t)d;
  }
}

// ---------------- edge2: 5-tile pipelined, sorted; segment-list epilogue ----------------
__global__ __launch_bounds__(512, 4) void edge2_kernel(
    const float* __restrict__ ea, const uint64_t* __restrict__ esd,
    const unsigned short* __restrict__ W1cs,
    const unsigned short* __restrict__ Xad, const unsigned short* __restrict__ Xb,
    float* __restrict__ agg) {
  __shared__ __align__(16) unsigned short Bs[16384];   // 32KB W1c, loaded once
  __shared__ __align__(16) unsigned short As[8192];    // 16KB ea tile; Ms(bf16) aliases
  __shared__ __align__(16) unsigned short Xbs[8192];   // 16KB Xb[src] rows
  __shared__ int dlds[64];
  __shared__ int segs[66];
  __shared__ int nsegS;
  unsigned short* Ms = As;   // post-MFMA alias

  const int t = threadIdx.x, l = t & 63, w = t >> 6;
  const int wm = w >> 2, wn = w & 3;       // 2x4 waves, 32x32 output tiles
  int bid = blockIdx.x;
  const int nwg = NEDGES / (64 * PT), q = nwg >> 3, r8 = nwg & 7;
  int xcd = bid & 7, off = bid >> 3;
  int wg = (xcd < r8) ? xcd * (q + 1) + off : r8 * (q + 1) + (xcd - r8) * q + off;
  const int base = wg * (64 * PT);
  const int r = t >> 3, o = t & 7;         // staging: row r (0..63), octant o

  // ---- B: raw copy of pre-swizzled bf16 W1c (once per block) ----
  {
    const u16x8* wsrc = (const u16x8*)W1cs;
    u16x8* bdst = (u16x8*)Bs;
#pragma unroll
    for (int i = 0; i < 4; ++i) bdst[t + i * 512] = wsrc[t + i * 512];
  }

  // ---- prologue prefetch: tile 0 data + tile 1 esd ----
  uint64_t v0 = esd[base + r];
  uint64_t vn = (PT > 1) ? esd[base + 64 + r] : 0;
  uint64_t vn2;
  float4 a0, a1, a2, a3;
  u16x8 x0, x1;
  {
    int e = (int)(v0 >> 32);
    const float* rowp = ea + (size_t)e * DIM + o * 16;
    a0 = *(const float4*)(rowp);
    a1 = *(const float4*)(rowp + 4);
    a2 = *(const float4*)(rowp + 8);
    a3 = *(const float4*)(rowp + 12);
    int s = (int)((v0 >> 16) & 0xFFFF);
    const u16x8* xr = (const u16x8*)(Xb + (size_t)s * DIM);
    x0 = xr[o * 2];
    x1 = xr[o * 2 + 1];
  }

  for (int tt = 0; tt < PT; ++tt) {
    const int p0 = base + tt * 64;
    // ---- stage: consume prefetched regs ----
    if (o == 0) dlds[r] = (int)(v0 & 0xFFFF);
    {
      const int swz = (r & 7) << 3;
      u32x4 g0 = {cvtpk(a0.x, a0.y), cvtpk(a0.z, a0.w), cvtpk(a1.x, a1.y), cvtpk(a1.z, a1.w)};
      u32x4 g1 = {cvtpk(a2.x, a2.y), cvtpk(a2.z, a2.w), cvtpk(a3.x, a3.y), cvtpk(a3.z, a3.w)};
      *(u32x4*)(As + ((r * 128 + o * 16) ^ swz)) = g0;
      *(u32x4*)(As + ((r * 128 + o * 16 + 8) ^ swz)) = g1;
      int sw = ((r >> 2) & 3) << 1;        // u16x8-unit swizzle
      u16x8* xb8 = (u16x8*)Xbs;
      xb8[r * 16 + ((o * 2) ^ sw)] = x0;
      xb8[r * 16 + ((o * 2 + 1) ^ sw)] = x1;
    }
    // ---- issue next tile's gathers (fly across MFMA+epilogue+segsum) ----
    if (tt < PT - 1) {
      int e = (int)(vn >> 32);
      const float* rowp = ea + (size_t)e * DIM + o * 16;
      a0 = *(const float4*)(rowp);
      a1 = *(const float4*)(rowp + 4);
      a2 = *(const float4*)(rowp + 8);
      a3 = *(const float4*)(rowp + 12);
      int s = (int)((vn >> 16) & 0xFFFF);
      const u16x8* xr = (const u16x8*)(Xb + (size_t)s * DIM);
      x0 = xr[o * 2];
      x1 = xr[o * 2 + 1];
    }
    if (tt < PT - 2) vn2 = esd[base + (tt + 2) * 64 + r];
    __syncthreads();                       // bar1: As/Xbs/dlds ready

    // ---- wave 0: segment boundaries from dlds ----
    if (w == 0) {
      int d = dlds[l];
      int dp = __shfl_up(d, 1);
      bool st = (l == 0) || (d != dp);
      uint64_t m = __ballot(st);
      int rank = (l == 0) ? 0 : __popcll(m & ((1ull << l) - 1ull));
      if (st) segs[rank] = l;
      if (l == 0) { int ns = __popcll(m); nsegS = ns; segs[ns] = 64; }
    }

    // ---- MFMA: 64x128 tile, K=128 ----
    f32x4 acc[2][2] = {};
#pragma unroll
    for (int kk = 0; kk < 4; ++kk) {
      bf16x8 a[2], b[2];
#pragma unroll
      for (int mi = 0; mi < 2; ++mi) {
        int row = wm * 32 + mi * 16 + (l & 15);
        int idx = (row * 128 + kk * 32 + (l >> 4) * 8) ^ ((row & 7) << 3);
        a[mi] = *(const bf16x8*)(As + idx);
      }
#pragma unroll
      for (int ni = 0; ni < 2; ++ni) {
        int n = wn * 32 + ni * 16 + (l & 15);
        int idx = (n * 128 + kk * 32 + (l >> 4) * 8) ^ ((n & 7) << 3);
        b[ni] = *(const bf16x8*)(Bs + idx);
      }
#pragma unroll
      for (int mi = 0; mi < 2; ++mi)
#pragma unroll
        for (int ni = 0; ni < 2; ++ni)
          acc[mi][ni] = __builtin_amdgcn_mfma_f32_16x16x32_bf16(a[mi], b[ni], acc[mi][ni], 0, 0, 0);
    }
    __syncthreads();                       // bar2: As dead -> Ms writable

    // ---- epilogue: relu(acc + Xad[dst] + Xbs) -> Ms (bf16, in As region) ----
#pragma unroll
    for (int mi = 0; mi < 2; ++mi)
#pragma unroll
      for (int rr = 0; rr < 4; ++rr) {
        int m = wm * 32 + mi * 16 + (l >> 4) * 4 + rr;
        int d = dlds[m];
        const unsigned short* xa = Xad + (size_t)d * DIM;
        int cx = ((m >> 2) & 3) << 4;      // u16-element swizzle
#pragma unroll
        for (int ni = 0; ni < 2; ++ni) {
          int col = wn * 32 + ni * 16 + (l & 15);
          float vv = acc[mi][ni][rr] + bf2f(xa[col]) + bf2f(Xbs[m * 128 + (col ^ cx)]);
          Ms[m * 128 + (col ^ cx)] = f2bf(fmaxf(vv, 0.0f));
        }
      }
    __syncthreads();                       // bar3: Ms ready

    // ---- segment-list sum: one dst-run per (wave, col pair) ----
    {
      int nseg = nsegS;
      for (int sc = w; sc < nseg; sc += 8) {
        int beg = segs[sc], end = segs[sc + 1];
        int d = dlds[beg];
        float* arow = agg + (size_t)d * DIM;
        bool interior = (sc > 0) && (sc < nseg - 1);
#pragma unroll
        for (int cc = 0; cc < 2; ++cc) {
          int col = l + cc * 64;
          float s = 0.0f;
          for (int r2 = beg; r2 < end; ++r2)
            s += bf2f(Ms[r2 * 128 + (col ^ (((r2 >> 2) & 3) << 4))]);
          if (interior) arow[col] = s;
          else unsafeAtomicAdd(arow + col, s);
        }
      }
    }
    __syncthreads();                       // bar4: Ms consumed; loop
    v0 = vn; vn = vn2;
  }
}

// ---------------- edge (unsorted fallback) ----------------
__global__ __launch_bounds__(256, 2) void edge_kernel(
    const float* __restrict__ ea, const int* __restrict__ srcI, const int* __restrict__ dstI,
    const unsigned short* __restrict__ W1cs,
    const unsigned short* __restrict__ Xad, const unsigned short* __restrict__ Xb,
    float* __restrict__ agg) {
  __shared__ __align__(16) unsigned short As[128 * 128];
  __shared__ __align__(16) unsigned short Bs[128 * 128];
  const int t = threadIdx.x, l = t & 63, w = t >> 6, wm = w >> 1, wn = w & 1;
  const int e0 = blockIdx.x * 128, r = t >> 1, h = t & 1;
  const int swz = (r & 7) << 3;
  {
    const float* rowp = ea + (size_t)(e0 + r) * DIM + h * 64;
#pragma unroll
    for (int i = 0; i < 8; ++i) cvt8(rowp + i * 8, As, (r * 128 + h * 64 + i * 8) ^ swz);
  }
  {
    const u16x8* wsrc = (const u16x8*)W1cs;
    u16x8* bdst = (u16x8*)Bs;
#pragma unroll
    for (int i = 0; i < 8; ++i) bdst[t + i * 256] = wsrc[t + i * 256];
  }
  __syncthreads();
  f32x4 acc[4][4] = {};
  mfma128(As, Bs, acc, wm, wn, l);
#pragma unroll
  for (int mi = 0; mi < 4; ++mi)
#pragma unroll
    for (int rr = 0; rr < 4; ++rr) {
      int m = wm * 64 + mi * 16 + (l >> 4) * 4 + rr;
      int e = e0 + m;
      int d = dstI[e], s = srcI[e];
      const unsigned short* xa = Xad + (size_t)d * DIM;
      const unsigned short* xb = Xb + (size_t)s * DIM;
      float* ag = agg + (size_t)d * DIM;
#pragma unroll
      for (int ni = 0; ni < 4; ++ni) {
        int col = wn * 64 + ni * 16 + (l & 15);
        float v = acc[mi][ni][rr] + bf2f(xa[col]) + bf2f(xb[col]);
        unsafeAtomicAdd(ag + col, fmaxf(v, 0.0f));
      }
    }
}

// ---------------- node: out = relu( agg@W2b^T + Yx ) ----------------
__global__ __launch_bounds__(256, 2) void node_kernel(
    const float* __restrict__ agg, const unsigned short* __restrict__ Wt,
    const unsigned short* __restrict__ Yx, float* __restrict__ out) {
  __shared__ __align__(16) unsigned short As[128 * 128];
  __shared__ __align__(16) unsigned short Bs[128 * 128];
  const int t = threadIdx.x, l = t & 63, w = t >> 6, wm = w >> 1, wn = w & 1;
  const int n0 = blockIdx.x * 128, r = t >> 1, h = t & 1;
  const int swz = (r & 7) << 3;
  {
    int n = n0 + r; if (n >= NNODES) n = NNODES - 1;
    const float* rowp = agg + (size_t)n * DIM + h * 64;
#pragma unroll
    for (int i = 0; i < 8; ++i) cvt8(rowp + i * 8, As, (r * 128 + h * 64 + i * 8) ^ swz);
  }
  {
    const u16x8* wsrc = (const u16x8*)(Wt + (size_t)4 * 16384);   // W2 agg-segment
    u16x8* bdst = (u16x8*)Bs;
#pragma unroll
    for (int i = 0; i < 8; ++i) bdst[t + i * 256] = wsrc[t + i * 256];
  }
  __syncthreads();
  f32x4 acc[4][4] = {};
  mfma128(As, Bs, acc, wm, wn, l);
#pragma unroll
  for (int mi = 0; mi < 4; ++mi)
#pragma unroll
    for (int rr = 0; rr < 4; ++rr) {
      int m = wm * 64 + mi * 16 + (l >> 4) * 4 + rr;
      int n = n0 + m;
      if (n < NNODES) {
        float* orow = out + (size_t)n * DIM;
#pragma unroll
        for (int ni = 0; ni < 4; ++ni) {
          int col = wn * 64 + ni * 16 + (l & 15);
          float v = acc[mi][ni][rr] + bf2f(Yx[(size_t)n * DIM + col]);
          orow[col] = fmaxf(v, 0.0f);
        }
      }
    }
}

extern "C" void kernel_launch(void* const* d_in, const int* in_sizes, int n_in,
                              void* d_out, int out_size, void* d_ws, size_t ws_size,
                              hipStream_t stream) {
  const float* x   = (const float*)d_in[0];
  const int* ei    = (const int*)d_in[1];
  const float* ea  = (const float*)d_in[2];
  const float* u   = (const float*)d_in[3];
  const int* batch = (const int*)d_in[4];
  const float* W1  = (const float*)d_in[5];
  const float* b1  = (const float*)d_in[6];
  const float* W2  = (const float*)d_in[7];
  const float* b2  = (const float*)d_in[8];
  float* out = (float*)d_out;
  const int* srcI = ei;
  const int* dstI = ei + NEDGES;

  const size_t XAD_B = (size_t)NNODES * DIM * 2;        // 12.8 MB each (bf16)
  const size_t U_B   = (size_t)64 * DIM * 4;
  const size_t WT_B  = (size_t)5 * 16384 * 2;           // 160 KB
  const size_t ESD_B = (size_t)NEDGES * 8;              // 6.4 MB
  const size_t CNT_B = (size_t)(NNODES + 64) * 4;
  const size_t BS_B  = 4096;
  const size_t need_base = 3 * XAD_B + 2 * U_B + WT_B;
  const size_t need_sort = need_base + ESD_B + 2 * CNT_B + 2 * BS_B;

  char* p = (char*)d_ws;
  unsigned short* Xad = (unsigned short*)p; p += XAD_B;
  unsigned short* Xb  = (unsigned short*)p; p += XAD_B;
  unsigned short* Yx  = (unsigned short*)p; p += XAD_B;
  float* Ud = (float*)p; p += U_B;
  float* Uc = (float*)p; p += U_B;
  unsigned short* Wt = (unsigned short*)p; p += WT_B;
  uint64_t* esd = (uint64_t*)p; p += ESD_B;
  int* count  = (int*)p; p += CNT_B;
  int* rowptr = (int*)p; p += CNT_B;
  int* bsum = (int*)p; p += BS_B;
  int* bpre = (int*)p;

  float* agg = out;   // node_kernel block reads/writes only its own 128-row slice
  const int nAgg4 = NNODES * DIM / 4;

  if (ws_size >= need_sort) {
    zero_kernel<<<2048, 256, 0, stream>>>((float4*)agg, nAgg4, count, NNODES + 64);
    hist_kernel<<<(NEDGES + 255) / 256, 256, 0, stream>>>(dstI, count);
    scan1_kernel<<<NSB, 256, 0, stream>>>(count, bsum);
    scan2_kernel<<<1, 256, 0, stream>>>(bsum, bpre);
    scan3_kernel<<<NSB, 256, 0, stream>>>(count, bpre, rowptr);
    scatter_kernel<<<(NEDGES + 255) / 256, 256, 0, stream>>>(srcI, dstI, rowptr, esd);
    wconv_p0_kernel<<<352, 256, 0, stream>>>(W1, W2, u, b1, b2, Wt, Ud, Uc);
    p1_kernel<<<(NNODES + 127) / 128, 256, 0, stream>>>(x, batch, Wt, Ud, Uc, Xad, Xb, Yx);
    edge2_kernel<<<NEDGES / (64 * PT), 512, 0, stream>>>(ea, esd, Wt + 2 * 16384, Xad, Xb, agg);
    node_kernel<<<(NNODES + 127) / 128, 256, 0, stream>>>(agg, Wt, Yx, out);
  } else if (ws_size >= need_base) {
    zero_kernel<<<2048, 256, 0, stream>>>((float4*)agg, nAgg4, (int*)Ud, 0);
    wconv_p0_kernel<<<352, 256, 0, stream>>>(W1, W2, u, b1, b2, Wt, Ud, Uc);
    p1_kernel<<<(NNODES + 127) / 128, 256, 0, stream>>>(x, batch, Wt, Ud, Uc, Xad, Xb, Yx);
    edge_kernel<<<NEDGES / 128, 256, 0, stream>>>(ea, srcI, dstI, Wt + 2 * 16384, Xad, Xb, agg);
    node_kernel<<<(NNODES + 127) / 128, 256, 0, stream>>>(agg, Wt, Yx, out);
  }
}

// Round 9
// 311.219 us; speedup vs baseline: 1.1797x; 1.1797x over previous
//
#include <hip/hip_runtime.h>
#include <stdint.h>

#define NNODES 50000
#define NEDGES 800000
#define DIM 128
#define IN1 512
#define IN2 384
#define NSB 196   // ceil(NNODES/256)

typedef __attribute__((ext_vector_type(8))) short bf16x8;
typedef __attribute__((ext_vector_type(8))) unsigned short u16x8;
typedef __attribute__((ext_vector_type(4))) float f32x4;
typedef __attribute__((ext_vector_type(4))) uint32_t u32x4;
typedef __attribute__((ext_vector_type(2))) uint32_t u32x2;

__device__ __forceinline__ unsigned short f2bf(float f) {
  union { float f; uint32_t u; } v; v.f = f;
  return (unsigned short)((v.u + 0x7FFFu + ((v.u >> 16) & 1u)) >> 16);
}
__device__ __forceinline__ float bf2f(unsigned short u) {
  union { uint32_t u; float f; } v; v.u = ((uint32_t)u) << 16;
  return v.f;
}
__device__ __forceinline__ uint32_t cvtpk(float lo, float hi) {
  uint32_t r;
  asm volatile("v_cvt_pk_bf16_f32 %0, %1, %2" : "=v"(r) : "v"(lo), "v"(hi));
  return r;
}

__device__ __forceinline__ void cvt8(const float* __restrict__ p, unsigned short* dst, int sidx) {
  float4 f0 = *(const float4*)(p);
  float4 f1 = *(const float4*)(p + 4);
  u16x8 o;
  o[0] = f2bf(f0.x); o[1] = f2bf(f0.y); o[2] = f2bf(f0.z); o[3] = f2bf(f0.w);
  o[4] = f2bf(f1.x); o[5] = f2bf(f1.y); o[6] = f2bf(f1.z); o[7] = f2bf(f1.w);
  *(u16x8*)(dst + sidx) = o;
}

// 128x128x128 macro-tile, 4 waves as 2x2 of 64x64 (p1/node/fallback)
__device__ __forceinline__ void mfma128(const unsigned short* As, const unsigned short* Bs,
                                        f32x4 acc[4][4], int wm, int wn, int l) {
#pragma unroll
  for (int kk = 0; kk < 4; ++kk) {
    bf16x8 a[4], b[4];
#pragma unroll
    for (int mi = 0; mi < 4; ++mi) {
      int row = wm * 64 + mi * 16 + (l & 15);
      int idx = (row * 128 + kk * 32 + (l >> 4) * 8) ^ ((row & 7) << 3);
      a[mi] = *(const bf16x8*)(As + idx);
    }
#pragma unroll
    for (int ni = 0; ni < 4; ++ni) {
      int nrow = wn * 64 + ni * 16 + (l & 15);
      int idx = (nrow * 128 + kk * 32 + (l >> 4) * 8) ^ ((nrow & 7) << 3);
      b[ni] = *(const bf16x8*)(Bs + idx);
    }
#pragma unroll
    for (int mi = 0; mi < 4; ++mi)
#pragma unroll
      for (int ni = 0; ni < 4; ++ni)
        acc[mi][ni] = __builtin_amdgcn_mfma_f32_16x16x32_bf16(a[mi], b[ni], acc[mi][ni], 0, 0, 0);
  }
}

// ---------------- zero: agg (float4) + count ----------------
__global__ void zero_kernel(float4* __restrict__ a, int n4, int* __restrict__ c, int nc) {
  int i = blockIdx.x * 256 + threadIdx.x;
  int stride = gridDim.x * 256;
  for (int k = i; k < n4; k += stride) a[k] = float4{0.f, 0.f, 0.f, 0.f};
  for (int k = i; k < nc; k += stride) c[k] = 0;
}

// ---------------- wconv+p0: 5 pre-swizzled bf16 weight tiles, plus Ud/Uc ----------------
__global__ void wconv_p0_kernel(const float* __restrict__ W1, const float* __restrict__ W2,
                                const float* __restrict__ u, const float* __restrict__ b1,
                                const float* __restrict__ b2,
                                unsigned short* __restrict__ Wt,
                                float* __restrict__ Ud, float* __restrict__ Uc) {
  int b = blockIdx.x;
  if (b < 320) {
    int t = b * 256 + threadIdx.x;
    int tile = t >> 14, rem = t & 16383, n = rem >> 7, k = rem & 127;
    float v = (tile < 3) ? W1[(size_t)n * IN1 + tile * 128 + k]
                         : W2[(size_t)n * IN2 + (tile - 3) * 128 + k];
    int lin = ((n * 128 + (k & ~7)) ^ ((n & 7) << 3)) | (k & 7);
    Wt[tile * 16384 + lin] = f2bf(v);
  } else {
    int g = (b - 320) * 2 + (threadIdx.x >> 7);
    int c = threadIdx.x & 127;
    const float* ur = u + (size_t)g * DIM;
    const float* w1 = W1 + (size_t)c * IN1 + 384;
    const float* w2 = W2 + (size_t)c * IN2 + 256;
    float s1 = b1[c], s2 = b2[c];
    for (int k = 0; k < DIM; ++k) { float uv = ur[k]; s1 += uv * w1[k]; s2 += uv * w2[k]; }
    Ud[g * DIM + c] = s1;
    Uc[g * DIM + c] = s2;
  }
}

// ---------------- P1: Xad/Xb/Yx per-node precompute (linear coalesced staging) ----------------
__global__ __launch_bounds__(256, 2) void p1_kernel(
    const float* __restrict__ x, const int* __restrict__ batch,
    const unsigned short* __restrict__ Wt,
    const float* __restrict__ Ud, const float* __restrict__ Uc,
    unsigned short* __restrict__ Xad, unsigned short* __restrict__ Xb,
    unsigned short* __restrict__ Yx) {
  __shared__ __align__(16) unsigned short As[128 * 128];
  __shared__ __align__(16) unsigned short Bs[128 * 128];
  const int t = threadIdx.x, l = t & 63, w = t >> 6, wm = w >> 1, wn = w & 1;
  const int n0 = blockIdx.x * 128;
#pragma unroll
  for (int i = 0; i < 16; ++i) {
    int idx = i * 256 + t;               // float4 index within 128x128 tile
    int row = idx >> 5;                  // 32 float4 per row
    int c = (idx & 31) * 4;              // element col
    int n = n0 + row; if (n >= NNODES) n = NNODES - 1;
    float4 f = *(const float4*)(x + (size_t)n * DIM + c);
    u32x2 g = {cvtpk(f.x, f.y), cvtpk(f.z, f.w)};
    *(u32x2*)(As + (row * 128 + (c ^ ((row & 7) << 3)))) = g;
  }
#pragma unroll
  for (int p = 0; p < 3; ++p) {
    __syncthreads();
    {
      const u16x8* wsrc = (const u16x8*)(Wt + (size_t)((p == 2) ? 3 : p) * 16384);
      u16x8* bdst = (u16x8*)Bs;
#pragma unroll
      for (int i = 0; i < 8; ++i) bdst[t + i * 256] = wsrc[t + i * 256];
    }
    __syncthreads();
    f32x4 acc[4][4] = {};
    mfma128(As, Bs, acc, wm, wn, l);
#pragma unroll
    for (int mi = 0; mi < 4; ++mi)
#pragma unroll
      for (int rr = 0; rr < 4; ++rr) {
        int m = wm * 64 + mi * 16 + (l >> 4) * 4 + rr;
        int n = n0 + m;
        if (n < NNODES) {
          int g = batch[n];
#pragma unroll
          for (int ni = 0; ni < 4; ++ni) {
            int col = wn * 64 + ni * 16 + (l & 15);
            float v = acc[mi][ni][rr];
            if (p == 0)      Xad[(size_t)n * DIM + col] = f2bf(v + Ud[g * DIM + col]);
            else if (p == 1) Xb [(size_t)n * DIM + col] = f2bf(v);
            else             Yx [(size_t)n * DIM + col] = f2bf(v + Uc[g * DIM + col]);
          }
        }
      }
  }
}

// ---------------- counting sort by dst ----------------
__global__ void hist_kernel(const int* __restrict__ dstI, int* __restrict__ count) {
  int e = blockIdx.x * 256 + threadIdx.x;
  if (e < NEDGES) atomicAdd(&count[dstI[e]], 1);
}

__global__ void scan1_kernel(const int* __restrict__ count, int* __restrict__ bsum) {
  __shared__ int ws[4];
  int i = blockIdx.x * 256 + threadIdx.x;
  int v = (i < NNODES) ? count[i] : 0;
  int l = threadIdx.x & 63;
#pragma unroll
  for (int off = 32; off > 0; off >>= 1) v += __shfl_down(v, off);
  if (l == 0) ws[threadIdx.x >> 6] = v;
  __syncthreads();
  if (threadIdx.x == 0) bsum[blockIdx.x] = ws[0] + ws[1] + ws[2] + ws[3];
}

__global__ void scan2_kernel(const int* __restrict__ bsum, int* __restrict__ bpre) {
  __shared__ int s[256];
  int i = threadIdx.x;
  int v = (i < NSB) ? bsum[i] : 0;
  s[i] = v; __syncthreads();
  for (int off = 1; off < 256; off <<= 1) {
    int u = (i >= off) ? s[i - off] : 0;
    __syncthreads();
    s[i] += u;
    __syncthreads();
  }
  if (i < NSB) bpre[i] = s[i] - v;   // exclusive
}

__global__ void scan3_kernel(const int* __restrict__ count, const int* __restrict__ bpre,
                             int* __restrict__ rowptr) {
  __shared__ int s[256];
  int b = blockIdx.x, i = threadIdx.x, g = b * 256 + i;
  int v = (g < NNODES) ? count[g] : 0;
  s[i] = v; __syncthreads();
  for (int off = 1; off < 256; off <<= 1) {
    int u = (i >= off) ? s[i - off] : 0;
    __syncthreads();
    s[i] += u;
    __syncthreads();
  }
  if (g < NNODES) rowptr[g] = bpre[b] + s[i] - v;  // exclusive global prefix
}

// destructive on rowptr; one packed 8B write per edge: (e<<32)|(s<<16)|d
__global__ void scatter_kernel(const int* __restrict__ srcI, const int* __restrict__ dstI,
                               int* __restrict__ rowptr, uint64_t* __restrict__ esd) {
  int e = blockIdx.x * 256 + threadIdx.x;
  if (e < NEDGES) {
    int d = dstI[e], s = srcI[e];
    int pos = atomicAdd(&rowptr[d], 1);
    esd[pos] = ((uint64_t)(uint32_t)e << 32) | ((uint32_t)s << 16) | (uint32_t)d;
  }
}

// ---------------- edge2: 64-edge sorted tiles; per-instruction-contiguous gathers ----------------
__global__ __launch_bounds__(512, 6) void edge2_kernel(
    const float* __restrict__ ea, const uint64_t* __restrict__ esd,
    const unsigned short* __restrict__ W1cs,
    const unsigned short* __restrict__ Xad, const unsigned short* __restrict__ Xb,
    float* __restrict__ agg) {
  __shared__ __align__(16) unsigned short smem[24576];   // 48KB
  __shared__ int dlds[64];
  __shared__ int segs[66];
  __shared__ int nsegS;
  unsigned short* As  = smem;              // 16KB (ea tile)
  unsigned short* Bs  = smem + 8192;       // 32KB (W1c)
  unsigned short* Xbs = smem;              // post-MFMA alias of As (16KB)
  float* Ms = (float*)(smem + 8192);       // post-MFMA alias of Bs (32KB f32)

  const int t = threadIdx.x, l = t & 63, w = t >> 6;
  const int wm = w >> 2, wn = w & 3;       // 2x4 waves, 32x32 output tiles
  int bid = blockIdx.x;
  const int nwg = NEDGES / 64, q = nwg >> 3, r8 = nwg & 7;
  int xcd = bid & 7, off = bid >> 3;
  int wg = (xcd < r8) ? xcd * (q + 1) + off : r8 * (q + 1) + (xcd - r8) * q + off;
  const int p0 = wg * 64;
  const int r = t >> 3, o = t & 7;         // staging: row r (0..63), chunk o (0..7)
  const int swz = (r & 7) << 3;

  // ---- phase 1 ----
  // B: raw copy of pre-swizzled bf16 W1c
  {
    const u16x8* wsrc = (const u16x8*)W1cs;
    u16x8* bdst = (u16x8*)Bs;
#pragma unroll
    for (int i = 0; i < 4; ++i) bdst[t + i * 512] = wsrc[t + i * 512];
  }
  // esd word for this row (8 lanes broadcast-read the same address)
  uint64_t v = esd[p0 + r];
  if (o == 0) dlds[r] = (int)(v & 0xFFFF);
  // A: gather ea rows — per-instruction contiguous: lanes o cover one 128B line per row
  {
    int e = (int)(v >> 32);
    const float* rowp = ea + (size_t)e * DIM + o * 4;
    float4 f0 = *(const float4*)(rowp);          // bytes [o*16, +16) of line 0
    float4 f1 = *(const float4*)(rowp + 32);     // line 1
    float4 f2 = *(const float4*)(rowp + 64);     // line 2
    float4 f3 = *(const float4*)(rowp + 96);     // line 3
    u32x2 g0 = {cvtpk(f0.x, f0.y), cvtpk(f0.z, f0.w)};
    u32x2 g1 = {cvtpk(f1.x, f1.y), cvtpk(f1.z, f1.w)};
    u32x2 g2 = {cvtpk(f2.x, f2.y), cvtpk(f2.z, f2.w)};
    u32x2 g3 = {cvtpk(f3.x, f3.y), cvtpk(f3.z, f3.w)};
    *(u32x2*)(As + (r * 128 + ((o * 4      ) ^ swz))) = g0;
    *(u32x2*)(As + (r * 128 + ((o * 4 +  32) ^ swz))) = g1;
    *(u32x2*)(As + (r * 128 + ((o * 4 +  64) ^ swz))) = g2;
    *(u32x2*)(As + (r * 128 + ((o * 4 +  96) ^ swz))) = g3;
  }
  // Xb rows: issue contiguous loads early (write to LDS after MFMA)
  u16x8 x0, x1;
  {
    int s = (int)((v >> 16) & 0xFFFF);
    const u16x8* xr = (const u16x8*)(Xb + (size_t)s * DIM);
    x0 = xr[o];          // bytes [o*16, +16)      (lanes cover 128B contiguous)
    x1 = xr[o + 8];      // bytes [128 + o*16, +16)
  }
  __syncthreads();                         // bar1: As/Bs/dlds ready

  // wave 0: segment boundaries from dlds
  if (w == 0) {
    int d = dlds[l];
    int dp = __shfl_up(d, 1);
    bool st = (l == 0) || (d != dp);
    uint64_t m = __ballot(st);
    int rank = (l == 0) ? 0 : __popcll(m & ((1ull << l) - 1ull));
    if (st) segs[rank] = l;
    if (l == 0) { int ns = __popcll(m); nsegS = ns; segs[ns] = 64; }
  }

  // ---- MFMA: 64x128 tile, K=128 ----
  f32x4 acc[2][2] = {};
#pragma unroll
  for (int kk = 0; kk < 4; ++kk) {
    bf16x8 a[2], b[2];
#pragma unroll
    for (int mi = 0; mi < 2; ++mi) {
      int row = wm * 32 + mi * 16 + (l & 15);
      int idx = (row * 128 + kk * 32 + (l >> 4) * 8) ^ ((row & 7) << 3);
      a[mi] = *(const bf16x8*)(As + idx);
    }
#pragma unroll
    for (int ni = 0; ni < 2; ++ni) {
      int n = wn * 32 + ni * 16 + (l & 15);
      int idx = (n * 128 + kk * 32 + (l >> 4) * 8) ^ ((n & 7) << 3);
      b[ni] = *(const bf16x8*)(Bs + idx);
    }
#pragma unroll
    for (int mi = 0; mi < 2; ++mi)
#pragma unroll
      for (int ni = 0; ni < 2; ++ni)
        acc[mi][ni] = __builtin_amdgcn_mfma_f32_16x16x32_bf16(a[mi], b[ni], acc[mi][ni], 0, 0, 0);
  }
  __syncthreads();                         // bar2: As/Bs dead

  // ---- write Xb rows into LDS (chunk-swizzled, element-XOR cx = ((r>>2)&3)<<4) ----
  {
    int cx = ((r >> 2) & 3) << 4;
    *(u16x8*)(Xbs + (r * 128 + ((o * 8     ) ^ cx))) = x0;
    *(u16x8*)(Xbs + (r * 128 + ((o * 8 + 64) ^ cx))) = x1;
  }
  __syncthreads();                         // bar3: Xbs ready

  // ---- epilogue: v = acc + Xad[dst][col] (cache-hot) + Xbs ; relu -> Ms(f32) ----
#pragma unroll
  for (int mi = 0; mi < 2; ++mi)
#pragma unroll
    for (int rr = 0; rr < 4; ++rr) {
      int m = wm * 32 + mi * 16 + (l >> 4) * 4 + rr;
      int d = dlds[m];
      const unsigned short* xa = Xad + (size_t)d * DIM;
      int cs = ((m >> 2) & 3) << 3;        // f32-element swizzle for Ms
      int cx = ((m >> 2) & 3) << 4;        // u16-element swizzle for Xbs
#pragma unroll
      for (int ni = 0; ni < 2; ++ni) {
        int col = wn * 32 + ni * 16 + (l & 15);
        float vv = acc[mi][ni][rr] + bf2f(xa[col]) + bf2f(Xbs[m * 128 + (col ^ cx)]);
        Ms[m * 128 + (col ^ cs)] = fmaxf(vv, 0.0f);
      }
    }
  __syncthreads();                         // bar4: Ms ready

  // ---- segment-list sum: one dst-run per (wave, col pair) ----
  {
    int nseg = nsegS;
    for (int sc = w; sc < nseg; sc += 8) {
      int beg = segs[sc], end = segs[sc + 1];
      int d = dlds[beg];
      float* arow = agg + (size_t)d * DIM;
      bool interior = (sc > 0) && (sc < nseg - 1);
#pragma unroll
      for (int cc = 0; cc < 2; ++cc) {
        int col = l + cc * 64;
        float s = 0.0f;
        for (int r2 = beg; r2 < end; ++r2)
          s += Ms[r2 * 128 + (col ^ (((r2 >> 2) & 3) << 3))];
        if (interior) arow[col] = s;
        else unsafeAtomicAdd(arow + col, s);
      }
    }
  }
}

// ---------------- edge (unsorted fallback) ----------------
__global__ __launch_bounds__(256, 2) void edge_kernel(
    const float* __restrict__ ea, const int* __restrict__ srcI, const int* __restrict__ dstI,
    const unsigned short* __restrict__ W1cs,
    const unsigned short* __restrict__ Xad, const unsigned short* __restrict__ Xb,
    float* __restrict__ agg) {
  __shared__ __align__(16) unsigned short As[128 * 128];
  __shared__ __align__(16) unsigned short Bs[128 * 128];
  const int t = threadIdx.x, l = t & 63, w = t >> 6, wm = w >> 1, wn = w & 1;
  const int e0 = blockIdx.x * 128, r = t >> 1, h = t & 1;
  const int swz = (r & 7) << 3;
  {
    const float* rowp = ea + (size_t)(e0 + r) * DIM + h * 64;
#pragma unroll
    for (int i = 0; i < 8; ++i) cvt8(rowp + i * 8, As, (r * 128 + h * 64 + i * 8) ^ swz);
  }
  {
    const u16x8* wsrc = (const u16x8*)W1cs;
    u16x8* bdst = (u16x8*)Bs;
#pragma unroll
    for (int i = 0; i < 8; ++i) bdst[t + i * 256] = wsrc[t + i * 256];
  }
  __syncthreads();
  f32x4 acc[4][4] = {};
  mfma128(As, Bs, acc, wm, wn, l);
#pragma unroll
  for (int mi = 0; mi < 4; ++mi)
#pragma unroll
    for (int rr = 0; rr < 4; ++rr) {
      int m = wm * 64 + mi * 16 + (l >> 4) * 4 + rr;
      int e = e0 + m;
      int d = dstI[e], s = srcI[e];
      const unsigned short* xa = Xad + (size_t)d * DIM;
      const unsigned short* xb = Xb + (size_t)s * DIM;
      float* ag = agg + (size_t)d * DIM;
#pragma unroll
      for (int ni = 0; ni < 4; ++ni) {
        int col = wn * 64 + ni * 16 + (l & 15);
        float v = acc[mi][ni][rr] + bf2f(xa[col]) + bf2f(xb[col]);
        unsafeAtomicAdd(ag + col, fmaxf(v, 0.0f));
      }
    }
}

// ---------------- node: out = relu( agg@W2b^T + Yx ) (linear coalesced staging) ----------------
__global__ __launch_bounds__(256, 2) void node_kernel(
    const float* __restrict__ agg, const unsigned short* __restrict__ Wt,
    const unsigned short* __restrict__ Yx, float* __restrict__ out) {
  __shared__ __align__(16) unsigned short As[128 * 128];
  __shared__ __align__(16) unsigned short Bs[128 * 128];
  const int t = threadIdx.x, l = t & 63, w = t >> 6, wm = w >> 1, wn = w & 1;
  const int n0 = blockIdx.x * 128;
#pragma unroll
  for (int i = 0; i < 16; ++i) {
    int idx = i * 256 + t;
    int row = idx >> 5;
    int c = (idx & 31) * 4;
    int n = n0 + row; if (n >= NNODES) n = NNODES - 1;
    float4 f = *(const float4*)(agg + (size_t)n * DIM + c);
    u32x2 g = {cvtpk(f.x, f.y), cvtpk(f.z, f.w)};
    *(u32x2*)(As + (row * 128 + (c ^ ((row & 7) << 3)))) = g;
  }
  {
    const u16x8* wsrc = (const u16x8*)(Wt + (size_t)4 * 16384);   // W2 agg-segment
    u16x8* bdst = (u16x8*)Bs;
#pragma unroll
    for (int i = 0; i < 8; ++i) bdst[t + i * 256] = wsrc[t + i * 256];
  }
  __syncthreads();
  f32x4 acc[4][4] = {};
  mfma128(As, Bs, acc, wm, wn, l);
#pragma unroll
  for (int mi = 0; mi < 4; ++mi)
#pragma unroll
    for (int rr = 0; rr < 4; ++rr) {
      int m = wm * 64 + mi * 16 + (l >> 4) * 4 + rr;
      int n = n0 + m;
      if (n < NNODES) {
        float* orow = out + (size_t)n * DIM;
#pragma unroll
        for (int ni = 0; ni < 4; ++ni) {
          int col = wn * 64 + ni * 16 + (l & 15);
          float v = acc[mi][ni][rr] + bf2f(Yx[(size_t)n * DIM + col]);
          orow[col] = fmaxf(v, 0.0f);
        }
      }
    }
}

extern "C" void kernel_launch(void* const* d_in, const int* in_sizes, int n_in,
                              void* d_out, int out_size, void* d_ws, size_t ws_size,
                              hipStream_t stream) {
  const float* x   = (const float*)d_in[0];
  const int* ei    = (const int*)d_in[1];
  const float* ea  = (const float*)d_in[2];
  const float* u   = (const float*)d_in[3];
  const int* batch = (const int*)d_in[4];
  const float* W1  = (const float*)d_in[5];
  const float* b1  = (const float*)d_in[6];
  const float* W2  = (const float*)d_in[7];
  const float* b2  = (const float*)d_in[8];
  float* out = (float*)d_out;
  const int* srcI = ei;
  const int* dstI = ei + NEDGES;

  const size_t XAD_B = (size_t)NNODES * DIM * 2;        // 12.8 MB each (bf16)
  const size_t U_B   = (size_t)64 * DIM * 4;
  const size_t WT_B  = (size_t)5 * 16384 * 2;           // 160 KB
  const size_t ESD_B = (size_t)NEDGES * 8;              // 6.4 MB
  const size_t CNT_B = (size_t)(NNODES + 64) * 4;
  const size_t BS_B  = 4096;
  const size_t need_base = 3 * XAD_B + 2 * U_B + WT_B;
  const size_t need_sort = need_base + ESD_B + 2 * CNT_B + 2 * BS_B;

  char* p = (char*)d_ws;
  unsigned short* Xad = (unsigned short*)p; p += XAD_B;
  unsigned short* Xb  = (unsigned short*)p; p += XAD_B;
  unsigned short* Yx  = (unsigned short*)p; p += XAD_B;
  float* Ud = (float*)p; p += U_B;
  float* Uc = (float*)p; p += U_B;
  unsigned short* Wt = (unsigned short*)p; p += WT_B;
  uint64_t* esd = (uint64_t*)p; p += ESD_B;
  int* count  = (int*)p; p += CNT_B;
  int* rowptr = (int*)p; p += CNT_B;
  int* bsum = (int*)p; p += BS_B;
  int* bpre = (int*)p;

  float* agg = out;   // node_kernel block reads/writes only its own 128-row slice
  const int nAgg4 = NNODES * DIM / 4;

  if (ws_size >= need_sort) {
    zero_kernel<<<2048, 256, 0, stream>>>((float4*)agg, nAgg4, count, NNODES + 64);
    hist_kernel<<<(NEDGES + 255) / 256, 256, 0, stream>>>(dstI, count);
    scan1_kernel<<<NSB, 256, 0, stream>>>(count, bsum);
    scan2_kernel<<<1, 256, 0, stream>>>(bsum, bpre);
    scan3_kernel<<<NSB, 256, 0, stream>>>(count, bpre, rowptr);
    scatter_kernel<<<(NEDGES + 255) / 256, 256, 0, stream>>>(srcI, dstI, rowptr, esd);
    wconv_p0_kernel<<<352, 256, 0, stream>>>(W1, W2, u, b1, b2, Wt, Ud, Uc);
    p1_kernel<<<(NNODES + 127) / 128, 256, 0, stream>>>(x, batch, Wt, Ud, Uc, Xad, Xb, Yx);
    edge2_kernel<<<NEDGES / 64, 512, 0, stream>>>(ea, esd, Wt + 2 * 16384, Xad, Xb, agg);
    node_kernel<<<(NNODES + 127) / 128, 256, 0, stream>>>(agg, Wt, Yx, out);
  } else if (ws_size >= need_base) {
    zero_kernel<<<2048, 256, 0, stream>>>((float4*)agg, nAgg4, (int*)Ud, 0);
    wconv_p0_kernel<<<352, 256, 0, stream>>>(W1, W2, u, b1, b2, Wt, Ud, Uc);
    p1_kernel<<<(NNODES + 127) / 128, 256, 0, stream>>>(x, batch, Wt, Ud, Uc, Xad, Xb, Yx);
    edge_kernel<<<NEDGES / 128, 256, 0, stream>>>(ea, srcI, dstI, Wt + 2 * 16384, Xad, Xb, agg);
    node_kernel<<<(NNODES + 127) / 128, 256, 0, stream>>>(agg, Wt, Yx, out);
  }
}